// Round 14
// baseline (35.502 us; speedup 1.0000x reference)
//
#include <hip/hip_runtime.h>

#define D_MODEL 1024
#define N_MOD   4

typedef float fx4 __attribute__((ext_vector_type(4)));

// ============ Stage (R13-proven, comm-free): Weff = Wr . Wg ============
__global__ __launch_bounds__(256) void weff_skinny_kernel(
    const fx4*   __restrict__ Wg4,   // [1024][256] fx4
    const float* __restrict__ Wr,    // [4][1024]
    fx4*         __restrict__ Weff4) // [4][256] fx4
{
    const int t   = threadIdx.x;
    const int es  = t >> 1;               // 0..127
    const int c   = t & 1;                // 0..1
    const int col = blockIdx.x * 2 + c;   // fx4-column 0..255

    fx4 acc[N_MOD];
    #pragma unroll
    for (int m = 0; m < N_MOD; ++m) acc[m] = (fx4)(0.f);

    #pragma unroll
    for (int k = 0; k < 8; ++k) {
        const int e = es + k * 128;
        const fx4 wg = Wg4[e * 256 + col];
        #pragma unroll
        for (int m = 0; m < N_MOD; ++m)
            acc[m] += Wr[m * D_MODEL + e] * wg;
    }

    __shared__ fx4 red[2][N_MOD][128];          // 16KB
    #pragma unroll
    for (int m = 0; m < N_MOD; ++m) red[c][m][es] = acc[m];
    __syncthreads();

    const int p  = t >> 5;
    const int c2 = p & 1;
    const int m2 = p >> 1;
    const int e5 = t & 31;
    fx4 s = red[c2][m2][e5]      + red[c2][m2][e5 + 32]
          + red[c2][m2][e5 + 64] + red[c2][m2][e5 + 96];

    #pragma unroll
    for (int off = 16; off; off >>= 1) {
        s.x += __shfl_xor(s.x, off, 64);
        s.y += __shfl_xor(s.y, off, 64);
        s.z += __shfl_xor(s.z, off, 64);
        s.w += __shfl_xor(s.w, off, 64);
    }
    if (e5 == 0)
        Weff4[m2 * 256 + blockIdx.x * 2 + c2] = s;
}

// ============ Main v6: LDS-Weff (natural VGPR), 4 rows/wave, 2048 blocks ============
// Same math as R8; w4 register cache (64 VGPR) replaced by LDS reads so the
// compiler lands at ~60 VGPR -> ~7-8 waves/SIMD (vs 4) for latency hiding.
__global__ __launch_bounds__(256) void router_main_kernel(
    const float* __restrict__ h,     // [B, 1024]
    const float* __restrict__ Weff,  // [4, 1024]
    float* __restrict__ out,         // [4][B][4]
    int B)
{
    __shared__ fx4 wlds[N_MOD][4][64];    // [m][c][lane], 16 KB
    const int t = threadIdx.x;

    const fx4* __restrict__ W4 = (const fx4*)Weff;
    #pragma unroll
    for (int j = 0; j < 4; ++j)
        ((fx4*)wlds)[j * 256 + t] = W4[j * 256 + t];
    __syncthreads();

    const int lane = t & 63;
    const int wave = t >> 6;
    float4* __restrict__ out4 = (float4*)out;   // [4][B] float4s
    const int row0 = (blockIdx.x * 4 + wave) * 4;
    if (row0 >= B) return;

    const fx4* __restrict__ hb = (const fx4*)(h + (size_t)row0 * D_MODEL);

    float acc[4][N_MOD];
    #pragma unroll
    for (int i = 0; i < 4; ++i)
        #pragma unroll
        for (int m = 0; m < N_MOD; ++m) acc[i][m] = 0.f;

    #pragma unroll
    for (int c = 0; c < 4; ++c) {
        const fx4 v0 = hb[0 * 256 + c * 64 + lane];
        const fx4 v1 = hb[1 * 256 + c * 64 + lane];
        const fx4 v2 = hb[2 * 256 + c * 64 + lane];
        const fx4 v3 = hb[3 * 256 + c * 64 + lane];
        #pragma unroll
        for (int m = 0; m < N_MOD; ++m) {
            const fx4 w = wlds[m][c][lane];
            acc[0][m] = fmaf(v0.x, w.x, fmaf(v0.y, w.y, fmaf(v0.z, w.z, fmaf(v0.w, w.w, acc[0][m]))));
            acc[1][m] = fmaf(v1.x, w.x, fmaf(v1.y, w.y, fmaf(v1.z, w.z, fmaf(v1.w, w.w, acc[1][m]))));
            acc[2][m] = fmaf(v2.x, w.x, fmaf(v2.y, w.y, fmaf(v2.z, w.z, fmaf(v2.w, w.w, acc[2][m]))));
            acc[3][m] = fmaf(v3.x, w.x, fmaf(v3.y, w.y, fmaf(v3.z, w.z, fmaf(v3.w, w.w, acc[3][m]))));
        }
    }

    unsigned mask = 0;
    #pragma unroll
    for (int i = 0; i < 4; ++i) {
        // Fold 4 module streams into lane%4, then butterfly: 7 shuffles.
        const bool b0 = lane & 1;
        const float aa = (b0 ? acc[i][1] : acc[i][0])
                       + __shfl_xor(b0 ? acc[i][0] : acc[i][1], 1, 64);
        const float cc = (b0 ? acc[i][3] : acc[i][2])
                       + __shfl_xor(b0 ? acc[i][2] : acc[i][3], 1, 64);
        const bool b1 = lane & 2;
        float r = (b1 ? cc : aa) + __shfl_xor(b1 ? aa : cc, 2, 64);
        r += __shfl_xor(r, 4, 64);
        r += __shfl_xor(r, 8, 64);
        r += __shfl_xor(r, 16, 64);
        r += __shfl_xor(r, 32, 64);
        // r = logit of module lane&3, replicated per 4-lane group
        float mx = fmaxf(r, __shfl_xor(r, 1, 64));
        mx = fmaxf(mx, __shfl_xor(mx, 2, 64));
        const float ex = expf(r - mx);        // argmax lane: exactly 1.0
        float S = ex + __shfl_xor(ex, 1, 64);
        S += __shfl_xor(S, 2, 64);
        // prob_m > 0.5  <=>  m == argmax && S < 2  (ties -> S>=2 -> false)
        const bool hi = (r == mx) && (S < 2.0f);
        mask |= (hi ? 1u : 0u) << i;
    }

    // lanes 0-15 write 64B per module: m = l>>2, row offset l&3
    const int m  = lane >> 2;
    const int rs = lane & 3;
    const unsigned mm = __shfl(mask, m, 64);  // lane m holds module m's mask
    if (lane < 16) {
        const bool hi = (mm >> rs) & 1;
        const float4 val = hi ? make_float4(0.5f, 0.5f, 0.f, 0.f)
                              : make_float4(1.f, 0.f, 0.f, 0.f);
        out4[(size_t)m * B + row0 + rs] = val;
    }
}

extern "C" void kernel_launch(void* const* d_in, const int* in_sizes, int n_in,
                              void* d_out, int out_size, void* d_ws, size_t ws_size,
                              hipStream_t stream) {
    const float* h  = (const float*)d_in[0];   // [B, 1024]
    const fx4*   Wg = (const fx4*)d_in[1];     // [1024, 1024] floats
    const float* Wr = (const float*)d_in[2];   // [4, 1024]
    float* out = (float*)d_out;                // [4][B][4]

    const int B = in_sizes[0] / D_MODEL;       // 32768

    float* Weff = (float*)d_ws;                // 16 KB

    weff_skinny_kernel<<<128, 256, 0, stream>>>(Wg, Wr, (fx4*)Weff);

    const int grid = (B + 4 * 4 - 1) / (4 * 4); // 2048 for B=32768
    router_main_kernel<<<grid, 256, 0, stream>>>(h, Weff, out, B);
}